// Round 2
// baseline (707.291 us; speedup 1.0000x reference)
//
#include <hip/hip_runtime.h>
#include <math.h>

// E2M1 (MXFP4) block weight quantizer, block=32, layer_max=6.0.
// Outputs concatenated in d_out (float32):
//   [0, N)        deq_weight          N = 8192*8192
//   [N, 2N)       encoded (0..15 as float)
//   [2N, 2N+B)    e8m0_scale + 127    B = N/32
//   [2N+B, 2N+2B) eps_base = 0.5*tanh(eps_param)
//
// R4: theory revision. R3's issue/ILP attack was null -> kernel is NOT
// VALU/issue bound (arith: ~140 VALU/thread = ~30us chip-wide). Timed region
// = poison fill (~349us) + aux harness dispatches + kernel (~160-190us, near
// the 131us BW roofline). This version restores R2's proven fully-coalesced
// layout (R3 had 64B holes per instruction -> +18us) and keeps the cheap math:
//  - 8 lanes/block x one float4: every load/store = 4KB contiguous per wave.
//  - ILP-2 without breaking coalescing: thread t handles chunk t and chunk
//    t + NELEM/8 (two distant halves; both streams per-instruction contiguous,
//    two independent dependency chains, half the waves of R2).
//  - e8m0 = ceil(max(log2(a/6), -127)) bit-exact from the IEEE quotient's
//    exponent/mantissa bits (no v_log_f32, no ceilf; descale = a/6.0f IEEE
//    division matches the reference ulp-for-ulp, extraction then EXACT).
//  - tanh via v_exp_f32 + v_rcp_f32 (abs err ~1e-7, accepted class).
//  - mantissa via packed nibble LUT 0xC8643210 = 2*{0,.5,1,1.5,2,3,4,6};
//    deq = ldexp(+-nib, e-1) (exact: tiny int * pow2).
//  - plain (cached) loads/stores: match the fill's 6.33 TB/s write path;
//    nontemporal was part of R3's regression bundle.

typedef float f32x4 __attribute__((ext_vector_type(4)));

constexpr unsigned long long NELEM = 8192ull * 8192ull;       // 67108864
constexpr unsigned           NBLK  = (unsigned)(NELEM / 32);  // 2097152
constexpr unsigned           NTHREADS = (unsigned)(NELEM / 8);// 8388608

__device__ __forceinline__ void process4(
    const f32x4 wv, const float p,
    float& e_f, float& ep, f32x4& dq, f32x4& ec)
{
    // block amax: 4 local |.| maxes (abs folds into v_max modifiers),
    // butterfly across the aligned 8-lane group (3 shuffles).
    float a = fmaxf(fmaxf(fabsf(wv[0]), fabsf(wv[1])),
                    fmaxf(fabsf(wv[2]), fabsf(wv[3])));
    a = fmaxf(a, __shfl_xor(a, 1));
    a = fmaxf(a, __shfl_xor(a, 2));
    a = fmaxf(a, __shfl_xor(a, 4));

    // e8m0 = ceil(max(log2(a/6), -127)), bit-exact.
    // For normal descale = m*2^(ex-127), m in [1,2):
    //   ceil(log2) = (ex-127) + (mantissa_bits != 0)
    // ex==0 covers descale==0 (-inf -> -127) and denormals (clamp; off-by-one
    // only possible below ~1e-37, unreachable for N(0,0.05) weights).
    const float descale = a / 6.0f;
    const unsigned du = __float_as_uint(descale);   // sign bit always 0
    const int ex = (int)(du >> 23);
    int e = ex - 127 + ((du & 0x7fffffu) ? 1 : 0);
    e = (ex == 0) ? -127 : e;
    e = (e < -127) ? -127 : e;
    e_f = (float)(e + 127);
    const float rscale = ldexpf(1.0f, -e);          // exact 2^-e

    // eps = 0.5*tanh(p) = 0.5*sign(p)*(1-e^-2|p|)/(1+e^-2|p|)
    const float t  = fabsf(p);
    const float em = __expf(-2.0f * t);             // v_exp_f32 path
    const float th = (1.0f - em) * __builtin_amdgcn_rcpf(1.0f + em);
    ep = 0.5f * copysignf(th, p);

#pragma unroll
    for (int i = 0; i < 4; ++i) {
        const float wn = wv[i] * rscale;            // exact pow2 mul
        const float as = fmaxf(fabsf(wn) + ep, 0.0f);
        // threshold-count encode against E2M1 bounds (exact fp32 compares)
        const int o = (as > 0.25f) + (as > 0.75f) + (as > 1.25f) + (as > 1.75f)
                    + (as > 2.5f)  + (as > 3.5f)  + (as > 5.0f);
        // sign(w_norm)=+1 -> 0; zero or negative -> 1 (floor((2-sign)/2))
        const bool neg = (wn <= 0.0f);
        // 2*E2M1_VALUES[o] = {0,1,2,3,4,6,8,12} packed as nibbles
        const int nib = (int)((0xC8643210u >> (o * 4)) & 0xFu);
        dq[i] = ldexpf((float)(neg ? -nib : nib), e - 1);  // exact
        ec[i] = (float)(o | (neg ? 8 : 0));
    }
}

__global__ __launch_bounds__(256) void e2m1_quant_kernel(
    const float* __restrict__ w,
    const float* __restrict__ eps_p,
    float* __restrict__ out)
{
    const unsigned tid = blockIdx.x * 256u + threadIdx.x;   // [0, NTHREADS)
    const unsigned b0  = tid >> 3;                          // first-half block
    const unsigned b1  = b0 + NBLK / 2;                     // second-half block
    const unsigned long long off0 = 4ull * tid;             // elem offset, half 0
    const unsigned long long off1 = off0 + NELEM / 2;       // elem offset, half 1

    // two independent 16B loads, both fully coalesced per instruction
    const f32x4 v0 = *reinterpret_cast<const f32x4*>(w + off0);
    const f32x4 v1 = *reinterpret_cast<const f32x4*>(w + off1);
    const float p0 = eps_p[b0];     // broadcast to the 8-lane group
    const float p1 = eps_p[b1];

    float e0f, e1f, ep0, ep1;
    f32x4 dq0, dq1, ec0, ec1;
    process4(v0, p0, e0f, ep0, dq0, ec0);
    process4(v1, p1, e1f, ep1, dq1, ec1);

    // stores: every instruction = 4KB contiguous per wave
    *reinterpret_cast<f32x4*>(out + off0) = dq0;
    *reinterpret_cast<f32x4*>(out + off1) = dq1;
    *reinterpret_cast<f32x4*>(out + NELEM + off0) = ec0;
    *reinterpret_cast<f32x4*>(out + NELEM + off1) = ec1;

    if ((tid & 7u) == 0) {
        out[2 * NELEM + b0]        = e0f;   // e8m0_scale_uint8 as float
        out[2 * NELEM + b1]        = e1f;
        out[2 * NELEM + NBLK + b0] = ep0;   // eps_base
        out[2 * NELEM + NBLK + b1] = ep1;
    }
}

extern "C" void kernel_launch(void* const* d_in, const int* in_sizes, int n_in,
                              void* d_out, int out_size, void* d_ws, size_t ws_size,
                              hipStream_t stream) {
    const float* w     = (const float*)d_in[0];   // weight_fp  [8192*8192]
    const float* eps_p = (const float*)d_in[1];   // eps_param  [2097152]
    float* out = (float*)d_out;

    const int block = 256;
    const int grid  = (int)(NTHREADS / (unsigned)block);    // 32768
    e2m1_quant_kernel<<<grid, block, 0, stream>>>(w, eps_p, out);
}